// Round 6
// baseline (51.770 us; speedup 1.0000x reference)
//
#include <hip/hip_runtime.h>

#define HOP      256
#define SAMPLES  262144
#define NBINS    513
#define NFRAMES  1024

__device__ __forceinline__ float2 cmul(float2 a, float2 b) {
  return make_float2(a.x * b.x - a.y * b.y, a.x * b.y + a.y * b.x);
}
__device__ __forceinline__ float2 lds_ld(const float2* p, int bo) {
  return *(const float2*)((const char*)p + bo);
}
__device__ __forceinline__ void lds_st(float2* p, int bo, float2 v) {
  *(float2*)((char*)p + bo) = v;
}
// swizzle: c = (H<<6)|(M<<3)|L -> (H<<6)|((M^(H&1))<<3)|(L^M)
__device__ __forceinline__ int swz(int c) {
  int H = c >> 6, M = (c >> 3) & 7, L = c & 7;
  return (H << 6) | ((M ^ (H & 1)) << 3) | (L ^ M);
}

// 8-point DFT, natural-order in/out, W = e^{-2pi i/8}
__device__ __forceinline__ void fft8(float2 v[8]) {
  const float R = 0.70710678118654752440f;
  float2 s0 = make_float2(v[0].x + v[4].x, v[0].y + v[4].y);
  float2 d0 = make_float2(v[0].x - v[4].x, v[0].y - v[4].y);
  float2 s1 = make_float2(v[1].x + v[5].x, v[1].y + v[5].y);
  float2 d1 = make_float2(v[1].x - v[5].x, v[1].y - v[5].y);
  float2 s2 = make_float2(v[2].x + v[6].x, v[2].y + v[6].y);
  float2 d2 = make_float2(v[2].x - v[6].x, v[2].y - v[6].y);
  float2 s3 = make_float2(v[3].x + v[7].x, v[3].y + v[7].y);
  float2 d3 = make_float2(v[3].x - v[7].x, v[3].y - v[7].y);
  float2 e1 = make_float2(R * (d1.x + d1.y), R * (d1.y - d1.x));
  float2 e2 = make_float2(d2.y, -d2.x);
  float2 e3 = make_float2(R * (d3.y - d3.x), R * (-d3.x - d3.y));
  float2 p0 = make_float2(s0.x + s2.x, s0.y + s2.y);
  float2 q0 = make_float2(s0.x - s2.x, s0.y - s2.y);
  float2 p1 = make_float2(s1.x + s3.x, s1.y + s3.y);
  float2 q1 = make_float2(s1.x - s3.x, s1.y - s3.y);
  float2 q1t = make_float2(q1.y, -q1.x);
  float2 p2 = make_float2(d0.x + e2.x, d0.y + e2.y);
  float2 q2 = make_float2(d0.x - e2.x, d0.y - e2.y);
  float2 p3 = make_float2(e1.x + e3.x, e1.y + e3.y);
  float2 q3 = make_float2(e1.x - e3.x, e1.y - e3.y);
  float2 q3t = make_float2(q3.y, -q3.x);
  v[0] = make_float2(p0.x + p1.x, p0.y + p1.y);
  v[4] = make_float2(p0.x - p1.x, p0.y - p1.y);
  v[2] = make_float2(q0.x + q1t.x, q0.y + q1t.y);
  v[6] = make_float2(q0.x - q1t.x, q0.y - q1t.y);
  v[1] = make_float2(p2.x + p3.x, p2.y + p3.y);
  v[5] = make_float2(p2.x - p3.x, p2.y - p3.y);
  v[3] = make_float2(q2.x + q3t.x, q2.y + q3t.y);
  v[7] = make_float2(q2.x - q3t.x, q2.y - q3t.y);
}

// per-(frame,bin) rfft unpack: given Zk=Z[k], Zm=Z[512-k], tw=W_1024^k
#define UNP(J, ZB, IK, IM, TW, XR1, XI1, XR2, XI2) {                 \
    const int ff = fb + (J);                                         \
    float2 Zk = lds_ld(ZB, (((ff) << 9) + ((IK) ^ (ff))) << 3);      \
    float2 Zm = lds_ld(ZB, (((ff) << 9) + ((IM) ^ (ff))) << 3);      \
    float xer  = 0.5f * (Zk.x + Zm.x);                               \
    float xei  = 0.5f * (Zk.y - Zm.y);                               \
    float xo_r = 0.5f * (Zk.y + Zm.y);                               \
    float xo_i = -0.5f * (Zk.x - Zm.x);                              \
    float ur = (TW).x * xo_r - (TW).y * xo_i;                        \
    float ui = (TW).x * xo_i + (TW).y * xo_r;                        \
    XR1 = xer + ur; XI1 = xei + ui; XR2 = xer - ur; XI2 = ui - xei; }

__global__ __launch_bounds__(1024, 4)   // 1 block/CU (128 KiB LDS), VGPR<=128
void stft_kernel(const float* __restrict__ x, const float* __restrict__ win,
                 float* __restrict__ out) {
  __shared__ float2 z[2 * 8192];   // 128 KiB: two 16-frame tile buffers

  const int t    = threadIdx.x;
  const int bid  = blockIdx.x;       // 256 blocks, 1 per CU
  const int b    = bid >> 4;         // batch
  const int tile0 = (bid & 15) << 2; // 4 tiles (of 16 frames) per block
  const float* xb = x + (size_t)b * SAMPLES;
  float* out_r = out;
  float* out_i = out + (size_t)16 * NBINS * NFRAMES;

  // ---- FFT-role constants (per thread, step-invariant) ----
  const int w   = t >> 6;    // wave = frame-in-tile
  const int u   = t & 63;    // lane
  const int g   = u >> 3, m2l = u & 7;
  const int A0    = (g << 3) | (m2l ^ g);
  const int B1w_e = (A0 ^ w) << 3;
  const int B1w_o = B1w_e ^ 64;
  const int C1    = (g << 6) | ((g & 1) << 3) | m2l;
  const int B1r   = (C1 ^ w) << 3;
  const int D0    = (g << 6) | ((m2l ^ (g & 1)) << 3) | m2l;
  const int B2r   = (D0 ^ w) << 3;
  const int F0    = (m2l << 3) | (g ^ m2l);
  const int B3_e  = (F0 ^ w) << 3;
  const int B3_o  = B3_e ^ 64;

  // hoisted stage twiddles (depend only on lane)
  float sn, cs;
  __sincosf((float)u * (-6.28318530717958647693f / 512.f), &sn, &cs);
  float2 s1w1 = make_float2(cs, sn);
  float2 s1w2 = cmul(s1w1, s1w1);
  float2 s1w3 = cmul(s1w2, s1w1);
  float2 s1w4 = cmul(s1w2, s1w2);
  float2 s1w5 = cmul(s1w4, s1w1);
  float2 s1w6 = cmul(s1w4, s1w2);
  float2 s1w7 = cmul(s1w4, s1w3);
  __sincosf((float)m2l * (-6.28318530717958647693f / 64.f), &sn, &cs);
  float2 s2w1 = make_float2(cs, sn);
  float2 s2w2 = cmul(s2w1, s2w1);
  float2 s2w3 = cmul(s2w2, s2w1);
  float2 s2w4 = cmul(s2w2, s2w2);
  float2 s2w5 = cmul(s2w4, s2w1);
  float2 s2w6 = cmul(s2w4, s2w2);
  float2 s2w7 = cmul(s2w4, s2w3);

  // ---- unpack-role constants (per thread, step-invariant) ----
  const int g4 = t & 3;        // frame group (4 frames each)
  const int fb = g4 << 2;      // first frame of group
  const int q  = t >> 2;       // bin 0..255
  const int ik = swz(q);
  const int im = swz((512 - q) & 511);
  __sincosf((float)q * (-6.28318530717958647693f / 1024.f), &sn, &cs);
  const float2 twq = make_float2(cs, sn);
  const size_t rowA = ((size_t)b * NBINS + q) * NFRAMES + fb;
  const size_t rowB = ((size_t)b * NBINS + (512 - q)) * NFRAMES + fb;

  for (int s = 0; s < 4; ++s) {
    // ---------- (1) issue global loads for tile s (early) ----------
    const int f0s  = (tile0 + s) << 4;
    const int fr   = f0s + w;
    const int base = fr * HOP - 384;   // pad_left = 384
    float2 rr[8];
    if (fr >= 2 && fr <= 1021) {
      const float2* xc = (const float2*)(xb + base);
      const float2* wc = (const float2*)win;
#pragma unroll
      for (int n1 = 0; n1 < 8; ++n1) {
        float2 xv = xc[(n1 << 6) + u];
        float2 wv = wc[(n1 << 6) + u];
        rr[n1] = make_float2(xv.x * wv.x, xv.y * wv.y);
      }
    } else {
#pragma unroll
      for (int n1 = 0; n1 < 8; ++n1) {
        int sidx = (n1 << 7) + 2 * u;
        int idx = base + sidx;
        float2 xv = make_float2(0.f, 0.f);
        if (idx >= 0 && idx < SAMPLES) xv = *(const float2*)(xb + idx);
        float2 wv = *(const float2*)(win + sidx);
        rr[n1] = make_float2(xv.x * wv.x, xv.y * wv.y);
      }
    }

    // ---------- (2) unpack + store tile s-1 (other buffer) ----------
    if (s > 0) {
      const float2* zb = z + (((s - 1) & 1) << 13);
      const int f0p = (tile0 + s - 1) << 4;
      float r1x, r1y, r1z, r1w, i1x, i1y, i1z, i1w;
      float r2x, r2y, r2z, r2w, i2x, i2y, i2z, i2w;
      UNP(0, zb, ik, im, twq, r1x, i1x, r2x, i2x)
      UNP(1, zb, ik, im, twq, r1y, i1y, r2y, i2y)
      UNP(2, zb, ik, im, twq, r1z, i1z, r2z, i2z)
      UNP(3, zb, ik, im, twq, r1w, i1w, r2w, i2w)
      *(float4*)(out_r + rowA + f0p) = make_float4(r1x, r1y, r1z, r1w);
      *(float4*)(out_i + rowA + f0p) = make_float4(i1x, i1y, i1z, i1w);
      *(float4*)(out_r + rowB + f0p) = make_float4(r2x, r2y, r2z, r2w);
      *(float4*)(out_i + rowB + f0p) = make_float4(i2x, i2y, i2z, i2w);
      if (q == 0) {  // bin k=256 (self-mirror): X[256] = conj(Z[256])
        const int ik6 = swz(256);
        const float2 tw6 = make_float2(0.f, -1.f);
        float a0, a1, a2, a3, c0, c1, c2, c3, d_, e_;
        UNP(0, zb, ik6, ik6, tw6, a0, c0, d_, e_)
        UNP(1, zb, ik6, ik6, tw6, a1, c1, d_, e_)
        UNP(2, zb, ik6, ik6, tw6, a2, c2, d_, e_)
        UNP(3, zb, ik6, ik6, tw6, a3, c3, d_, e_)
        size_t o6 = ((size_t)b * NBINS + 256) * NFRAMES + fb + f0p;
        *(float4*)(out_r + o6) = make_float4(a0, a1, a2, a3);
        *(float4*)(out_i + o6) = make_float4(c0, c1, c2, c3);
      }
    }

    // ---------- (3) FFT tile s into buffer (s&1) ----------
    {
      float2* zf = z + ((s & 1) << 13) + (w << 9);
      fft8(rr);
      rr[1] = cmul(rr[1], s1w1);
      rr[2] = cmul(rr[2], s1w2);
      rr[3] = cmul(rr[3], s1w3);
      rr[4] = cmul(rr[4], s1w4);
      rr[5] = cmul(rr[5], s1w5);
      rr[6] = cmul(rr[6], s1w6);
      rr[7] = cmul(rr[7], s1w7);
      lds_st(zf, B1w_e,        rr[0]);
      lds_st(zf, B1w_o +  512, rr[1]);
      lds_st(zf, B1w_e + 1024, rr[2]);
      lds_st(zf, B1w_o + 1536, rr[3]);
      lds_st(zf, B1w_e + 2048, rr[4]);
      lds_st(zf, B1w_o + 2560, rr[5]);
      lds_st(zf, B1w_e + 3072, rr[6]);
      lds_st(zf, B1w_o + 3584, rr[7]);

      float2 y[8];
#pragma unroll
      for (int m1 = 0; m1 < 8; ++m1) y[m1] = lds_ld(zf, B1r ^ (72 * m1));
      fft8(y);
      y[1] = cmul(y[1], s2w1);
      y[2] = cmul(y[2], s2w2);
      y[3] = cmul(y[3], s2w3);
      y[4] = cmul(y[4], s2w4);
      y[5] = cmul(y[5], s2w5);
      y[6] = cmul(y[6], s2w6);
      y[7] = cmul(y[7], s2w7);
#pragma unroll
      for (int j1 = 0; j1 < 8; ++j1) lds_st(zf, B1r ^ (72 * j1), y[j1]);

      float2 h[8];
#pragma unroll
      for (int m = 0; m < 8; ++m) h[m] = lds_ld(zf, B2r ^ (m << 3));
      fft8(h);
      lds_st(zf, B3_e,        h[0]);
      lds_st(zf, B3_o +  512, h[1]);
      lds_st(zf, B3_e + 1024, h[2]);
      lds_st(zf, B3_o + 1536, h[3]);
      lds_st(zf, B3_e + 2048, h[4]);
      lds_st(zf, B3_o + 2560, h[5]);
      lds_st(zf, B3_e + 3072, h[6]);
      lds_st(zf, B3_o + 3584, h[7]);
    }
    __syncthreads();
  }

  // ---------- epilogue: unpack + store tile 3 ----------
  {
    const float2* zb = z + ((3 & 1) << 13);
    const int f0p = (tile0 + 3) << 4;
    float r1x, r1y, r1z, r1w, i1x, i1y, i1z, i1w;
    float r2x, r2y, r2z, r2w, i2x, i2y, i2z, i2w;
    UNP(0, zb, ik, im, twq, r1x, i1x, r2x, i2x)
    UNP(1, zb, ik, im, twq, r1y, i1y, r2y, i2y)
    UNP(2, zb, ik, im, twq, r1z, i1z, r2z, i2z)
    UNP(3, zb, ik, im, twq, r1w, i1w, r2w, i2w)
    *(float4*)(out_r + rowA + f0p) = make_float4(r1x, r1y, r1z, r1w);
    *(float4*)(out_i + rowA + f0p) = make_float4(i1x, i1y, i1z, i1w);
    *(float4*)(out_r + rowB + f0p) = make_float4(r2x, r2y, r2z, r2w);
    *(float4*)(out_i + rowB + f0p) = make_float4(i2x, i2y, i2z, i2w);
    if (q == 0) {
      const int ik6 = swz(256);
      const float2 tw6 = make_float2(0.f, -1.f);
      float a0, a1, a2, a3, c0, c1, c2, c3, d_, e_;
      UNP(0, zb, ik6, ik6, tw6, a0, c0, d_, e_)
      UNP(1, zb, ik6, ik6, tw6, a1, c1, d_, e_)
      UNP(2, zb, ik6, ik6, tw6, a2, c2, d_, e_)
      UNP(3, zb, ik6, ik6, tw6, a3, c3, d_, e_)
      size_t o6 = ((size_t)b * NBINS + 256) * NFRAMES + fb + f0p;
      *(float4*)(out_r + o6) = make_float4(a0, a1, a2, a3);
      *(float4*)(out_i + o6) = make_float4(c0, c1, c2, c3);
    }
  }
}

extern "C" void kernel_launch(void* const* d_in, const int* in_sizes, int n_in,
                              void* d_out, int out_size, void* d_ws, size_t ws_size,
                              hipStream_t stream) {
  const float* x = (const float*)d_in[0];
  const float* w = (const float*)d_in[1];
  float* out = (float*)d_out;
  (void)in_sizes; (void)n_in; (void)out_size; (void)d_ws; (void)ws_size;
  stft_kernel<<<dim3(256), dim3(1024), 0, stream>>>(x, w, out);
}

// Round 7
// 38.936 us; speedup vs baseline: 1.3296x; 1.3296x over previous
//
#include <hip/hip_runtime.h>

#define HOP      256
#define SAMPLES  262144
#define NBINS    513
#define NFRAMES  1024
#define FPB      8    // frames per block, one wave per frame

// 4-bit frame XOR key (injective, varies bit3) — keeps unpack reads at the
// structural bank minimum with only 3 bits of frame index.
#define KF(f) ((((f) & 1) << 3) | (f))

__device__ __forceinline__ float2 cmul(float2 a, float2 b) {
  return make_float2(a.x * b.x - a.y * b.y, a.x * b.y + a.y * b.x);
}
__device__ __forceinline__ float2 lds_ld(const float2* p, int bo) {
  return *(const float2*)((const char*)p + bo);
}
__device__ __forceinline__ void lds_st(float2* p, int bo, float2 v) {
  *(float2*)((char*)p + bo) = v;
}
// swizzle: c = (H<<6)|(M<<3)|L -> (H<<6)|((M^(H&1))<<3)|(L^M)
__device__ __forceinline__ int swz(int c) {
  int H = c >> 6, M = (c >> 3) & 7, L = c & 7;
  return (H << 6) | ((M ^ (H & 1)) << 3) | (L ^ M);
}

// 8-point DFT, natural-order in/out, W = e^{-2pi i/8}
__device__ __forceinline__ void fft8(float2 v[8]) {
  const float R = 0.70710678118654752440f;
  float2 s0 = make_float2(v[0].x + v[4].x, v[0].y + v[4].y);
  float2 d0 = make_float2(v[0].x - v[4].x, v[0].y - v[4].y);
  float2 s1 = make_float2(v[1].x + v[5].x, v[1].y + v[5].y);
  float2 d1 = make_float2(v[1].x - v[5].x, v[1].y - v[5].y);
  float2 s2 = make_float2(v[2].x + v[6].x, v[2].y + v[6].y);
  float2 d2 = make_float2(v[2].x - v[6].x, v[2].y - v[6].y);
  float2 s3 = make_float2(v[3].x + v[7].x, v[3].y + v[7].y);
  float2 d3 = make_float2(v[3].x - v[7].x, v[3].y - v[7].y);
  float2 e1 = make_float2(R * (d1.x + d1.y), R * (d1.y - d1.x));
  float2 e2 = make_float2(d2.y, -d2.x);
  float2 e3 = make_float2(R * (d3.y - d3.x), R * (-d3.x - d3.y));
  float2 p0 = make_float2(s0.x + s2.x, s0.y + s2.y);
  float2 q0 = make_float2(s0.x - s2.x, s0.y - s2.y);
  float2 p1 = make_float2(s1.x + s3.x, s1.y + s3.y);
  float2 q1 = make_float2(s1.x - s3.x, s1.y - s3.y);
  float2 q1t = make_float2(q1.y, -q1.x);
  float2 p2 = make_float2(d0.x + e2.x, d0.y + e2.y);
  float2 q2 = make_float2(d0.x - e2.x, d0.y - e2.y);
  float2 p3 = make_float2(e1.x + e3.x, e1.y + e3.y);
  float2 q3 = make_float2(e1.x - e3.x, e1.y - e3.y);
  float2 q3t = make_float2(q3.y, -q3.x);
  v[0] = make_float2(p0.x + p1.x, p0.y + p1.y);
  v[4] = make_float2(p0.x - p1.x, p0.y - p1.y);
  v[2] = make_float2(q0.x + q1t.x, q0.y + q1t.y);
  v[6] = make_float2(q0.x - q1t.x, q0.y - q1t.y);
  v[1] = make_float2(p2.x + p3.x, p2.y + p3.y);
  v[5] = make_float2(p2.x - p3.x, p2.y - p3.y);
  v[3] = make_float2(q2.x + q3t.x, q2.y + q3t.y);
  v[7] = make_float2(q2.x - q3t.x, q2.y - q3t.y);
}

__global__ __launch_bounds__(512, 8)   // VGPR<=64 -> 4 blocks/CU (32 KiB LDS each)
void stft_kernel(const float* __restrict__ x, const float* __restrict__ win,
                 float* __restrict__ out) {
  __shared__ float2 z[FPB * 512];  // 32 KiB
  const int t  = threadIdx.x;
  const int b  = blockIdx.x >> 7;          // 128 tiles per batch
  const int f0 = (blockIdx.x & 127) * FPB;

  // ---------------- FFT phase: one wave per frame, all LDS intra-wave ------
  {
    const int w = t >> 6;     // wave = frame-in-tile (0..7)
    const int u = t & 63;     // lane
    const int g = u >> 3, m2l = u & 7;
    const int kw = KF(w);
    float2* zf = z + (w << 9);

    // closed-form swizzled addresses (bytes), layout = swz_slot ^ KF(frame):
    const int A0    = (g << 3) | (m2l ^ g);
    const int B1w_e = (A0 ^ kw) << 3;                             // ex1 write, even k1
    const int B1w_o = B1w_e ^ 64;                                 //            odd k1
    const int C1    = (g << 6) | ((g & 1) << 3) | m2l;
    const int B1r   = (C1 ^ kw) << 3;  // ex1 read / ex2 write: ^ (72*m1)
    const int D0    = (g << 6) | ((m2l ^ (g & 1)) << 3) | m2l;
    const int B2r   = (D0 ^ kw) << 3;  // ex2 read: ^ (m<<3)
    const int F0    = (m2l << 3) | (g ^ m2l);
    const int B3_e  = (F0 ^ kw) << 3;                             // st3 write, even j2
    const int B3_o  = B3_e ^ 64;                                  //            odd j2

    // ---- load + window (bounds check only in first/last tile) ----
    const float* xb = x + (size_t)b * SAMPLES;
    const int fr   = f0 + w;
    const int base = fr * HOP - 384;  // pad_left = 384
    float2 r[8];
    if (f0 != 0 && f0 != (NFRAMES - FPB)) {
      const float2* xc = (const float2*)(xb + base);
      const float2* wc = (const float2*)win;
#pragma unroll
      for (int n1 = 0; n1 < 8; ++n1) {
        float2 xv = xc[(n1 << 6) + u];
        float2 wv = wc[(n1 << 6) + u];
        r[n1] = make_float2(xv.x * wv.x, xv.y * wv.y);
      }
    } else {
#pragma unroll
      for (int n1 = 0; n1 < 8; ++n1) {
        int s = (n1 << 7) + 2 * u;
        int idx = base + s;
        float2 xv = make_float2(0.f, 0.f);
        if (idx >= 0 && idx < SAMPLES) xv = *(const float2*)(xb + idx);
        float2 wv = *(const float2*)(win + s);
        r[n1] = make_float2(xv.x * wv.x, xv.y * wv.y);
      }
    }

    // ---- stage 1: radix-8, twiddle W512^{u*k1} ----
    fft8(r);
    float sn, cs;
    __sincosf((float)u * (-6.28318530717958647693f / 512.f), &sn, &cs);
    {
      float2 w1 = make_float2(cs, sn);
      float2 w2 = cmul(w1, w1);
      float2 w3 = cmul(w2, w1);
      float2 w4 = cmul(w2, w2);
      r[1] = cmul(r[1], w1);
      r[2] = cmul(r[2], w2);
      r[3] = cmul(r[3], w3);
      r[4] = cmul(r[4], w4);
      r[5] = cmul(r[5], cmul(w4, w1));
      r[6] = cmul(r[6], cmul(w4, w2));
      r[7] = cmul(r[7], cmul(w4, w3));
    }
    lds_st(zf, B1w_e,        r[0]);
    lds_st(zf, B1w_o +  512, r[1]);
    lds_st(zf, B1w_e + 1024, r[2]);
    lds_st(zf, B1w_o + 1536, r[3]);
    lds_st(zf, B1w_e + 2048, r[4]);
    lds_st(zf, B1w_o + 2560, r[5]);
    lds_st(zf, B1w_e + 3072, r[6]);
    lds_st(zf, B1w_o + 3584, r[7]);

    // ex1 read: addr = B1r ^ 72*m1
    float2 y[8];
#pragma unroll
    for (int m1 = 0; m1 < 8; ++m1) y[m1] = lds_ld(zf, B1r ^ (72 * m1));

    // ---- stage 2: radix-8, twiddle W64^{m2l*j1} ----
    fft8(y);
    __sincosf((float)m2l * (-6.28318530717958647693f / 64.f), &sn, &cs);
    {
      float2 w1 = make_float2(cs, sn);
      float2 w2 = cmul(w1, w1);
      float2 w3 = cmul(w2, w1);
      float2 w4 = cmul(w2, w2);
      y[1] = cmul(y[1], w1);
      y[2] = cmul(y[2], w2);
      y[3] = cmul(y[3], w3);
      y[4] = cmul(y[4], w4);
      y[5] = cmul(y[5], cmul(w4, w1));
      y[6] = cmul(y[6], cmul(w4, w2));
      y[7] = cmul(y[7], cmul(w4, w3));
    }
    // ex2 write: same 8 addresses as ex1 read (in-place along m1/j1)
#pragma unroll
    for (int j1 = 0; j1 < 8; ++j1) lds_st(zf, B1r ^ (72 * j1), y[j1]);

    // ex2 read: addr = B2r ^ (m<<3)
    float2 h[8];
#pragma unroll
    for (int m = 0; m < 8; ++m) h[m] = lds_ld(zf, B2r ^ (m << 3));

    // ---- stage 3 + natural-order store: addr = base_even/odd + j2*512 ----
    fft8(h);
    lds_st(zf, B3_e,        h[0]);
    lds_st(zf, B3_o +  512, h[1]);
    lds_st(zf, B3_e + 1024, h[2]);
    lds_st(zf, B3_o + 1536, h[3]);
    lds_st(zf, B3_e + 2048, h[4]);
    lds_st(zf, B3_o + 2560, h[5]);
    lds_st(zf, B3_e + 3072, h[6]);
    lds_st(zf, B3_o + 3584, h[7]);
  }
  __syncthreads();

  // -------- unpack via conjugate symmetry + transposed coalesced write -----
  {
    const int f  = t & 7;    // frame-in-tile (lane-fastest -> 32B segments)
    const int q  = t >> 3;   // bin residue 0..63
    const int kf = KF(f);
    const int fr = f0 + f;
    const float2* zq = z + (f << 9);
    const int G    = ((q >> 3) << 3) | ((q & 7) ^ (q >> 3));  // swz(q), H=0
    const int BK_e = (G ^ kf) << 3;    // Zk read, even i
    const int BK_o = BK_e ^ 64;        //          odd i
    float* out_r = out;
    float* out_i = out + (size_t)16 * NBINS * NFRAMES;
    float sn, cs;
    __sincosf((float)q * (-6.28318530717958647693f / 1024.f), &sn, &cs);
    float2 tw = make_float2(cs, sn);
    // bin step 64: stp = W_1024^64 = e^{-i*pi/8}
    const float2 stp = make_float2(0.92387953251128675613f, -0.38268343236508977173f);
#pragma unroll
    for (int i = 0; i < 5; ++i) {
      int k = q + (i << 6);
      if (k > 256) break;
      float2 Zk = lds_ld(zq, ((i & 1) ? BK_o : BK_e) + i * 512);
      int mk = (512 - k) & 511;
      float2 Zm = lds_ld(zq, (swz(mk) ^ kf) << 3);
      float xer  = 0.5f * (Zk.x + Zm.x);
      float xei  = 0.5f * (Zk.y - Zm.y);
      float xor_ = 0.5f * (Zk.y + Zm.y);
      float xoi  = -0.5f * (Zk.x - Zm.x);
      float ur = tw.x * xor_ - tw.y * xoi;
      float ui = tw.x * xoi + tw.y * xor_;
      size_t o1 = ((size_t)b * NBINS + k) * NFRAMES + fr;
      size_t o2 = ((size_t)b * NBINS + (512 - k)) * NFRAMES + fr;
      out_r[o1] = xer + ur;
      out_i[o1] = xei + ui;
      out_r[o2] = xer - ur;
      out_i[o2] = ui - xei;
      tw = cmul(tw, stp);
    }
  }
}

extern "C" void kernel_launch(void* const* d_in, const int* in_sizes, int n_in,
                              void* d_out, int out_size, void* d_ws, size_t ws_size,
                              hipStream_t stream) {
  const float* x = (const float*)d_in[0];
  const float* w = (const float*)d_in[1];
  float* out = (float*)d_out;
  (void)in_sizes; (void)n_in; (void)out_size; (void)d_ws; (void)ws_size;
  stft_kernel<<<dim3(2048), dim3(512), 0, stream>>>(x, w, out);
}

// Round 8
// 24.410 us; speedup vs baseline: 2.1209x; 1.5951x over previous
//
#include <hip/hip_runtime.h>

#define HOP      256
#define SAMPLES  262144
#define NBINS    513
#define NFRAMES  1024
#define FPB      16   // frames per block, one wave per frame

__device__ __forceinline__ float2 cmul(float2 a, float2 b) {
  return make_float2(a.x * b.x - a.y * b.y, a.x * b.y + a.y * b.x);
}
__device__ __forceinline__ float2 lds_ld(const float2* p, int bo) {
  return *(const float2*)((const char*)p + bo);
}
__device__ __forceinline__ void lds_st(float2* p, int bo, float2 v) {
  *(float2*)((char*)p + bo) = v;
}
// swizzle: c = (H<<6)|(M<<3)|L -> (H<<6)|((M^(H&1))<<3)|(L^M)
__device__ __forceinline__ int swz(int c) {
  int H = c >> 6, M = (c >> 3) & 7, L = c & 7;
  return (H << 6) | ((M ^ (H & 1)) << 3) | (L ^ M);
}

// 8-point DFT, natural-order in/out, W = e^{-2pi i/8}
__device__ __forceinline__ void fft8(float2 v[8]) {
  const float R = 0.70710678118654752440f;
  float2 s0 = make_float2(v[0].x + v[4].x, v[0].y + v[4].y);
  float2 d0 = make_float2(v[0].x - v[4].x, v[0].y - v[4].y);
  float2 s1 = make_float2(v[1].x + v[5].x, v[1].y + v[5].y);
  float2 d1 = make_float2(v[1].x - v[5].x, v[1].y - v[5].y);
  float2 s2 = make_float2(v[2].x + v[6].x, v[2].y + v[6].y);
  float2 d2 = make_float2(v[2].x - v[6].x, v[2].y - v[6].y);
  float2 s3 = make_float2(v[3].x + v[7].x, v[3].y + v[7].y);
  float2 d3 = make_float2(v[3].x - v[7].x, v[3].y - v[7].y);
  float2 e1 = make_float2(R * (d1.x + d1.y), R * (d1.y - d1.x));
  float2 e2 = make_float2(d2.y, -d2.x);
  float2 e3 = make_float2(R * (d3.y - d3.x), R * (-d3.x - d3.y));
  float2 p0 = make_float2(s0.x + s2.x, s0.y + s2.y);
  float2 q0 = make_float2(s0.x - s2.x, s0.y - s2.y);
  float2 p1 = make_float2(s1.x + s3.x, s1.y + s3.y);
  float2 q1 = make_float2(s1.x - s3.x, s1.y - s3.y);
  float2 q1t = make_float2(q1.y, -q1.x);
  float2 p2 = make_float2(d0.x + e2.x, d0.y + e2.y);
  float2 q2 = make_float2(d0.x - e2.x, d0.y - e2.y);
  float2 p3 = make_float2(e1.x + e3.x, e1.y + e3.y);
  float2 q3 = make_float2(e1.x - e3.x, e1.y - e3.y);
  float2 q3t = make_float2(q3.y, -q3.x);
  v[0] = make_float2(p0.x + p1.x, p0.y + p1.y);
  v[4] = make_float2(p0.x - p1.x, p0.y - p1.y);
  v[2] = make_float2(q0.x + q1t.x, q0.y + q1t.y);
  v[6] = make_float2(q0.x - q1t.x, q0.y - q1t.y);
  v[1] = make_float2(p2.x + p3.x, p2.y + p3.y);
  v[5] = make_float2(p2.x - p3.x, p2.y - p3.y);
  v[3] = make_float2(q2.x + q3t.x, q2.y + q3t.y);
  v[7] = make_float2(q2.x - q3t.x, q2.y - q3t.y);
}

// unpack one (frame, bin): ZP = frame base, KEY = frame xor-key, SK/SM slots
#define UNPK(ZP, KEY, SK, SM, TW, R1, I1, R2, I2) {                  \
    float2 Zk = lds_ld(ZP, ((SK) ^ (KEY)) << 3);                     \
    float2 Zm = lds_ld(ZP, ((SM) ^ (KEY)) << 3);                     \
    float xer  = 0.5f * (Zk.x + Zm.x);                               \
    float xei  = 0.5f * (Zk.y - Zm.y);                               \
    float xo_r = 0.5f * (Zk.y + Zm.y);                               \
    float xo_i = -0.5f * (Zk.x - Zm.x);                              \
    float ur = (TW).x * xo_r - (TW).y * xo_i;                        \
    float ui = (TW).x * xo_i + (TW).y * xo_r;                        \
    R1 = xer + ur; I1 = xei + ui; R2 = xer - ur; I2 = ui - xei; }

__global__ __launch_bounds__(1024, 8)   // VGPR<=64 -> 2 blocks/CU
void stft_kernel(const float* __restrict__ x, const float* __restrict__ win,
                 float* __restrict__ out) {
  __shared__ float2 z[FPB * 512];  // 64 KiB
  const int t  = threadIdx.x;
  const int b  = blockIdx.x >> 6;
  const int f0 = (blockIdx.x & 63) * FPB;

  // ---------------- FFT phase: one wave per frame, all LDS intra-wave ------
  {
    const int w = t >> 6;     // wave = frame-in-tile
    const int u = t & 63;     // lane
    const int g = u >> 3, m2l = u & 7;
    float2* zf = z + (w << 9);

    // closed-form swizzled addresses (bytes), derived from swz():
    const int A0    = (g << 3) | (m2l ^ g);
    const int B1w_e = (A0 ^ w) << 3;                              // ex1 write, even k1
    const int B1w_o = B1w_e ^ 64;                                 //            odd k1
    const int C1    = (g << 6) | ((g & 1) << 3) | m2l;
    const int B1r   = (C1 ^ w) << 3;   // ex1 read / ex2 write: ^ (72*m1)
    const int D0    = (g << 6) | ((m2l ^ (g & 1)) << 3) | m2l;
    const int B2r   = (D0 ^ w) << 3;   // ex2 read: ^ (m<<3)
    const int F0    = (m2l << 3) | (g ^ m2l);
    const int B3_e  = (F0 ^ w) << 3;                              // st3 write, even j2
    const int B3_o  = B3_e ^ 64;                                  //            odd j2

    // ---- load + window (bounds check only in first/last tile) ----
    const float* xb = x + (size_t)b * SAMPLES;
    const int fr   = f0 + w;
    const int base = fr * HOP - 384;  // pad_left = 384
    float2 r[8];
    if (f0 != 0 && f0 != (NFRAMES - FPB)) {
      const float2* xc = (const float2*)(xb + base);
      const float2* wc = (const float2*)win;
#pragma unroll
      for (int n1 = 0; n1 < 8; ++n1) {
        float2 xv = xc[(n1 << 6) + u];
        float2 wv = wc[(n1 << 6) + u];
        r[n1] = make_float2(xv.x * wv.x, xv.y * wv.y);
      }
    } else {
#pragma unroll
      for (int n1 = 0; n1 < 8; ++n1) {
        int s = (n1 << 7) + 2 * u;
        int idx = base + s;
        float2 xv = make_float2(0.f, 0.f);
        if (idx >= 0 && idx < SAMPLES) xv = *(const float2*)(xb + idx);
        float2 wv = *(const float2*)(win + s);
        r[n1] = make_float2(xv.x * wv.x, xv.y * wv.y);
      }
    }

    // ---- stage 1: radix-8, twiddle W512^{u*k1} ----
    fft8(r);
    float sn, cs;
    __sincosf((float)u * (-6.28318530717958647693f / 512.f), &sn, &cs);
    {
      float2 w1 = make_float2(cs, sn);
      float2 w2 = cmul(w1, w1);
      float2 w3 = cmul(w2, w1);
      float2 w4 = cmul(w2, w2);
      r[1] = cmul(r[1], w1);
      r[2] = cmul(r[2], w2);
      r[3] = cmul(r[3], w3);
      r[4] = cmul(r[4], w4);
      r[5] = cmul(r[5], cmul(w4, w1));
      r[6] = cmul(r[6], cmul(w4, w2));
      r[7] = cmul(r[7], cmul(w4, w3));
    }
    lds_st(zf, B1w_e,        r[0]);
    lds_st(zf, B1w_o +  512, r[1]);
    lds_st(zf, B1w_e + 1024, r[2]);
    lds_st(zf, B1w_o + 1536, r[3]);
    lds_st(zf, B1w_e + 2048, r[4]);
    lds_st(zf, B1w_o + 2560, r[5]);
    lds_st(zf, B1w_e + 3072, r[6]);
    lds_st(zf, B1w_o + 3584, r[7]);

    // ex1 read: addr = B1r ^ 72*m1
    float2 y[8];
#pragma unroll
    for (int m1 = 0; m1 < 8; ++m1) y[m1] = lds_ld(zf, B1r ^ (72 * m1));

    // ---- stage 2: radix-8, twiddle W64^{m2l*j1} ----
    fft8(y);
    __sincosf((float)m2l * (-6.28318530717958647693f / 64.f), &sn, &cs);
    {
      float2 w1 = make_float2(cs, sn);
      float2 w2 = cmul(w1, w1);
      float2 w3 = cmul(w2, w1);
      float2 w4 = cmul(w2, w2);
      y[1] = cmul(y[1], w1);
      y[2] = cmul(y[2], w2);
      y[3] = cmul(y[3], w3);
      y[4] = cmul(y[4], w4);
      y[5] = cmul(y[5], cmul(w4, w1));
      y[6] = cmul(y[6], cmul(w4, w2));
      y[7] = cmul(y[7], cmul(w4, w3));
    }
    // ex2 write: same 8 addresses as ex1 read (in-place along m1/j1)
#pragma unroll
    for (int j1 = 0; j1 < 8; ++j1) lds_st(zf, B1r ^ (72 * j1), y[j1]);

    // ex2 read: addr = B2r ^ (m<<3)
    float2 h[8];
#pragma unroll
    for (int m = 0; m < 8; ++m) h[m] = lds_ld(zf, B2r ^ (m << 3));

    // ---- stage 3 + natural-order store: addr = base_even/odd + j2*512 ----
    fft8(h);
    lds_st(zf, B3_e,        h[0]);
    lds_st(zf, B3_o +  512, h[1]);
    lds_st(zf, B3_e + 1024, h[2]);
    lds_st(zf, B3_o + 1536, h[3]);
    lds_st(zf, B3_e + 2048, h[4]);
    lds_st(zf, B3_o + 2560, h[5]);
    lds_st(zf, B3_e + 3072, h[6]);
    lds_st(zf, B3_o + 3584, h[7]);
  }
  __syncthreads();

  // -------- unpack: frame-pair per thread, float2 stores, 2 bin-steps ------
  // thread owns frames {f, f+1} of bin q and q+128 (+ mirrors, + edge 256).
  {
    const int f2i = t & 7;        // frame-pair index: 8 lanes span 16 frames
    const int q   = t >> 3;       // bin 0..127
    const int f   = f2i << 1;
    const int fr  = f0 + f;
    const float2* zp0 = z + (f << 9);
    const float2* zp1 = z + ((f + 1) << 9);

    const int sk0 = swz(q);
    const int sm0 = swz((512 - q) & 511);
    const int sk1 = sk0 + 128;                   // swz(q+128) = swz(q)+128
    const int sm1 = (q == 0) ? 384 : (sm0 - 128);// swz(384-q); q=0 -> swz(384)

    float sn, cs;
    __sincosf((float)q * (-6.28318530717958647693f / 1024.f), &sn, &cs);
    const float2 tw0 = make_float2(cs, sn);
    // tw1 = W_1024^(q+128) = tw0 * e^{-i*pi/4}
    const float2 tw1 = cmul(tw0, make_float2(0.70710678118654752440f,
                                             -0.70710678118654752440f));
    float* out_r = out;
    float* out_i = out + (size_t)16 * NBINS * NFRAMES;
    const size_t o1 = ((size_t)b * NBINS + q) * NFRAMES + fr;
    const size_t o2 = ((size_t)b * NBINS + (512 - q)) * NFRAMES + fr;
    const size_t STP = (size_t)128 * NFRAMES;

    // ---- k = q ----
    {
      float r1a, i1a, r2a, i2a, r1b, i1b, r2b, i2b;
      UNPK(zp0, f,     sk0, sm0, tw0, r1a, i1a, r2a, i2a)
      UNPK(zp1, f + 1, sk0, sm0, tw0, r1b, i1b, r2b, i2b)
      *(float2*)(out_r + o1) = make_float2(r1a, r1b);
      *(float2*)(out_i + o1) = make_float2(i1a, i1b);
      *(float2*)(out_r + o2) = make_float2(r2a, r2b);
      *(float2*)(out_i + o2) = make_float2(i2a, i2b);
    }
    // ---- k = q + 128 ----
    {
      float r1a, i1a, r2a, i2a, r1b, i1b, r2b, i2b;
      UNPK(zp0, f,     sk1, sm1, tw1, r1a, i1a, r2a, i2a)
      UNPK(zp1, f + 1, sk1, sm1, tw1, r1b, i1b, r2b, i2b)
      *(float2*)(out_r + o1 + STP) = make_float2(r1a, r1b);
      *(float2*)(out_i + o1 + STP) = make_float2(i1a, i1b);
      *(float2*)(out_r + o2 - STP) = make_float2(r2a, r2b);
      *(float2*)(out_i + o2 - STP) = make_float2(i2a, i2b);
    }
    // ---- edge bin 256: X[256] = conj(Z[256]) ----
    if (q == 0) {
      float2 Za = lds_ld(zp0, (256 ^ f) << 3);
      float2 Zb = lds_ld(zp1, (256 ^ (f + 1)) << 3);
      const size_t o6 = ((size_t)b * NBINS + 256) * NFRAMES + fr;
      *(float2*)(out_r + o6) = make_float2(Za.x, Zb.x);
      *(float2*)(out_i + o6) = make_float2(-Za.y, -Zb.y);
    }
  }
}

extern "C" void kernel_launch(void* const* d_in, const int* in_sizes, int n_in,
                              void* d_out, int out_size, void* d_ws, size_t ws_size,
                              hipStream_t stream) {
  const float* x = (const float*)d_in[0];
  const float* w = (const float*)d_in[1];
  float* out = (float*)d_out;
  (void)in_sizes; (void)n_in; (void)out_size; (void)d_ws; (void)ws_size;
  stft_kernel<<<dim3(1024), dim3(1024), 0, stream>>>(x, w, out);
}